// Round 10
// baseline (7385.954 us; speedup 1.0000x reference)
//
#include <hip/hip_runtime.h>
#include <cstdint>
#include <cmath>

constexpr int BATCH = 64;
constexpr int T     = 512;
constexpr int N     = 1024;
constexpr int NWG   = 256;   // persistent workgroups (== CU count)
constexpr int NP    = N + 4; // padded LDS row

typedef float f4 __attribute__((ext_vector_type(4)));

struct alignas(128) PadInt { int v; int pad[31]; };
__device__ PadInt g_cnt[8];   // per-batch-group arrival counters (cumulative)
__device__ PadInt g_flag[8];  // per-batch-group completed-step counters

// ---- MALL-coherent access helpers (bypass L1+L2) ---------------------------
__device__ __forceinline__ f4 ld_sys_x4(const float* p) {
  f4 v;
  asm volatile("global_load_dwordx4 %0, %1, off sc0 sc1" : "=v"(v) : "v"(p));
  return v;  // NOT ready until wait_vm0()
}
__device__ __forceinline__ int ld_sys_i32(const int* p) {
  int v;
  asm volatile("global_load_dword %0, %1, off sc0 sc1\n\ts_waitcnt vmcnt(0)"
               : "=v"(v) : "v"(p) : "memory");
  return v;
}
__device__ __forceinline__ void st_sys_x4(float* p, f4 v) {
  asm volatile("global_store_dwordx4 %0, %1, off sc0 sc1 nt" ::"v"(p), "v"(v)
               : "memory");
}
__device__ __forceinline__ void wait_vm0(void) {
  asm volatile("s_waitcnt vmcnt(0)" ::: "memory");
  __builtin_amdgcn_sched_barrier(0);
}

__device__ __forceinline__ void arrive_cnt(int bg, int t) {
  int old = __hip_atomic_fetch_add(&g_cnt[bg].v, 1, __ATOMIC_RELAXED,
                                   __HIP_MEMORY_SCOPE_AGENT);
  if (old == t * 64 + 63)  // last arriver of this step: publish
    __hip_atomic_store(&g_flag[bg].v, t + 1, __ATOMIC_RELAXED,
                       __HIP_MEMORY_SCOPE_AGENT);
}
__device__ __forceinline__ void pollf(int bg, int e) {
  while (ld_sys_i32(&g_flag[bg].v) < e) __builtin_amdgcn_s_sleep(1);
}

// ---------------------------------------------------------------------------
// W_self = 0.5*(W + W^T); also re-initializes the barrier state.
// ---------------------------------------------------------------------------
__global__ __launch_bounds__(256) void symm_k(const float* __restrict__ W,
                                              float* __restrict__ Ws) {
  if (blockIdx.x == 0 && blockIdx.y == 0 && threadIdx.x < 8) {
    __hip_atomic_store(&g_cnt[threadIdx.x].v, 0, __ATOMIC_RELAXED,
                       __HIP_MEMORY_SCOPE_AGENT);
    __hip_atomic_store(&g_flag[threadIdx.x].v, 0, __ATOMIC_RELAXED,
                       __HIP_MEMORY_SCOPE_AGENT);
  }
  int j = blockIdx.x * 16 + (threadIdx.x & 15);
  int i = blockIdx.y * 16 + (threadIdx.x >> 4);
  Ws[(size_t)i * N + j] = 0.5f * (W[(size_t)i * N + j] + W[(size_t)j * N + i]);
}

// ---------------------------------------------------------------------------
// x_proj = A (M x K) . B^T, B = W_input (N x K) row-major. 128x128 tile.
// ---------------------------------------------------------------------------
__global__ __launch_bounds__(256) void xproj_gemm(const float* __restrict__ A,
                                                  const float* __restrict__ B,
                                                  float* __restrict__ C,
                                                  int M) {
  constexpr int BM = 128, BN = 128, BK = 16;
  __shared__ float As[BK][BM + 4];
  __shared__ float Bs[BK][BN + 4];

  const int tid = threadIdx.x;
  const int bm = blockIdx.y, bn = blockIdx.x;
  const int tx = tid & 15, ty = tid >> 4;
  const int K = N;

  float acc[8][8];
#pragma unroll
  for (int i = 0; i < 8; ++i)
#pragma unroll
    for (int j = 0; j < 8; ++j) acc[i][j] = 0.f;

  for (int kt = 0; kt < K; kt += BK) {
#pragma unroll
    for (int s = 0; s < 2; ++s) {
      int f = tid + s * 256;
      int row = f >> 2, kq = f & 3;
      float4 a = *reinterpret_cast<const float4*>(
          &A[(size_t)(bm * BM + row) * K + kt + kq * 4]);
      As[kq * 4 + 0][row] = a.x;
      As[kq * 4 + 1][row] = a.y;
      As[kq * 4 + 2][row] = a.z;
      As[kq * 4 + 3][row] = a.w;
      float4 b = *reinterpret_cast<const float4*>(
          &B[(size_t)(bn * BN + row) * K + kt + kq * 4]);
      Bs[kq * 4 + 0][row] = b.x;
      Bs[kq * 4 + 1][row] = b.y;
      Bs[kq * 4 + 2][row] = b.z;
      Bs[kq * 4 + 3][row] = b.w;
    }
    __syncthreads();

#pragma unroll
    for (int k = 0; k < BK; ++k) {
      float a[8], b[8];
      *reinterpret_cast<float4*>(&a[0]) =
          *reinterpret_cast<const float4*>(&As[k][ty * 8]);
      *reinterpret_cast<float4*>(&a[4]) =
          *reinterpret_cast<const float4*>(&As[k][ty * 8 + 4]);
      *reinterpret_cast<float4*>(&b[0]) =
          *reinterpret_cast<const float4*>(&Bs[k][tx * 8]);
      *reinterpret_cast<float4*>(&b[4]) =
          *reinterpret_cast<const float4*>(&Bs[k][tx * 8 + 4]);
#pragma unroll
      for (int i = 0; i < 8; ++i)
#pragma unroll
        for (int j = 0; j < 8; ++j) acc[i][j] = fmaf(a[i], b[j], acc[i][j]);
    }
    __syncthreads();
  }

#pragma unroll
  for (int i = 0; i < 8; ++i) {
    size_t row = (size_t)bm * BM + ty * 8 + i;
#pragma unroll
    for (int j = 0; j < 8; j += 4) {
      *reinterpret_cast<float4*>(&C[row * N + bn * BN + tx * 8 + j]) =
          *reinterpret_cast<const float4*>(&acc[i][j]);
    }
  }
}

// ---------------------------------------------------------------------------
// Persistent recurrence, pipelined dual-chain + W in registers.
// 256 WGs x 256 thr, 1 WG/CU (LDS 100 KiB).  WG (p = wg&3, cg = wg>>2):
// cols cg*16..+15 for batch groups bgA=2p, bgB=2p+1 (8 batches each).
// Thread micro-tile: 4 batches x 4 cols x 32 k-elems; W fragment (4 cols x
// 32 k = 32 f4) in VGPRs for all steps, shared by both chains.
// Per step: issue BOTH chains' staging loads, one vmcnt wait, one barrier,
// compute+store A (reducer lanes direct x4 store), compute+store B (A's
// store-ack hides here), one ack-wait, concurrent arrive+poll per chain.
// 8 independent 64-WG barriers, relaxed atomics, MALL-coherent data path.
// ---------------------------------------------------------------------------
__global__ __launch_bounds__(256, 1) void rnn_persist(
    float* __restrict__ out, const float* __restrict__ Ws) {
  const int tid = threadIdx.x;
  const int wg  = blockIdx.x;
  const int p   = wg & 3;
  const int cg  = wg >> 2;
  const int bgA = 2 * p, bgB = 2 * p + 1;
  const int m0  = cg * 16;
  const int b0A = bgA * 8, b0B = bgB * 8;
  const size_t TN = (size_t)T * N;

  // 100 KiB forced LDS (1 WG/CU).  W-staging phase aliases the h buffers.
  __shared__ __align__(16) char lds_raw[102400];
  float (*Wl)[NP] = reinterpret_cast<float(*)[NP]>(lds_raw);           // 16 rows
  float (*hA)[NP] = reinterpret_cast<float(*)[NP]>(lds_raw);           // 8 rows
  float (*hB)[NP] = reinterpret_cast<float(*)[NP]>(lds_raw + 8 * NP * 4);

  const int lane = tid & 63;
  const int v    = tid >> 6;
  const int kp   = lane >> 1;                  // k partition 0..31
  const int cq   = ((v >> 1) << 1) | (lane & 1);  // col quad 0..3
  const int bh   = v & 1;                      // batch half 0..1

  // ---- W slice -> LDS (coalesced) -> per-thread register fragment ----
#pragma unroll
  for (int r = 0; r < 16; ++r)
    *reinterpret_cast<float4*>(&Wl[r][tid * 4]) =
        *reinterpret_cast<const float4*>(&Ws[(size_t)(m0 + r) * N + tid * 4]);
  __syncthreads();
  f4 wreg[4][8];  // [ci][j]: W[m0+cq*4+ci][kp*4 + 128*j .. +3]
#pragma unroll
  for (int ci = 0; ci < 4; ++ci)
#pragma unroll
    for (int j = 0; j < 8; ++j)
      wreg[ci][j] =
          *reinterpret_cast<const f4*>(&Wl[cq * 4 + ci][kp * 4 + 128 * j]);
  __syncthreads();  // LDS now reused as hA/hB

  const int srow = tid >> 5;   // staging batch row 0..7
  const int scol = tid & 31;   // staging chunk

  const float* hbA = out + (size_t)(b0A + srow) * TN + 4 * scol;
  const float* hbB = out + (size_t)(b0B + srow) * TN + 4 * scol;
  // reducer-lane (lane<2) output base: 4 batches x cols [m0+cq*4, +4)
  float* obA = out + (size_t)(b0A + bh * 4) * TN + m0 + cq * 4;
  float* obB = out + (size_t)(b0B + bh * 4) * TN + m0 + cq * 4;

  // ---- t = 0: h_0 = tanh(x_proj_0) ----
  {
    f4 xA[4], xB[4];
    if (lane < 2) {
#pragma unroll
      for (int bi = 0; bi < 4; ++bi) {
        xA[bi] = ld_sys_x4(obA + (size_t)bi * TN);
        xB[bi] = ld_sys_x4(obB + (size_t)bi * TN);
      }
    }
    wait_vm0();
    if (lane < 2) {
#pragma unroll
      for (int bi = 0; bi < 4; ++bi) {
        f4 rA, rB;
        rA.x = tanhf(xA[bi].x); rA.y = tanhf(xA[bi].y);
        rA.z = tanhf(xA[bi].z); rA.w = tanhf(xA[bi].w);
        rB.x = tanhf(xB[bi].x); rB.y = tanhf(xB[bi].y);
        rB.z = tanhf(xB[bi].z); rB.w = tanhf(xB[bi].w);
        st_sys_x4(obA + (size_t)bi * TN, rA);
        st_sys_x4(obB + (size_t)bi * TN, rB);
      }
    }
    wait_vm0();
    __syncthreads();
    if (tid == 0)  { arrive_cnt(bgA, 0); pollf(bgA, 1); }
    if (tid == 64) { arrive_cnt(bgB, 0); pollf(bgB, 1); }
    __syncthreads();
  }

  for (int t = 1; t < T; ++t) {
    // ---- issue ALL staging loads (both chains) ----
    f4 tA[8], tB[8], xA[4], xB[4];
    const float* hsA = hbA + (size_t)(t - 1) * N;
    const float* hsB = hbB + (size_t)(t - 1) * N;
#pragma unroll
    for (int q = 0; q < 8; ++q) tA[q] = ld_sys_x4(hsA + 128 * q);
#pragma unroll
    for (int q = 0; q < 8; ++q) tB[q] = ld_sys_x4(hsB + 128 * q);
    if (lane < 2) {
#pragma unroll
      for (int bi = 0; bi < 4; ++bi) {
        xA[bi] = ld_sys_x4(obA + (size_t)bi * TN + (size_t)t * N);
        xB[bi] = ld_sys_x4(obB + (size_t)bi * TN + (size_t)t * N);
      }
    }
    wait_vm0();
#pragma unroll
    for (int q = 0; q < 8; ++q)
      *reinterpret_cast<f4*>(&hA[srow][4 * scol + 128 * q]) = tA[q];
#pragma unroll
    for (int q = 0; q < 8; ++q)
      *reinterpret_cast<f4*>(&hB[srow][4 * scol + 128 * q]) = tB[q];
    __syncthreads();

    // ================= chain A: compute + reduce + store =================
    {
      float acc[16];
#pragma unroll
      for (int i = 0; i < 16; ++i) acc[i] = 0.f;
#pragma unroll
      for (int j = 0; j < 8; ++j) {
        const int kb = kp * 4 + 128 * j;
        f4 hv[4];
#pragma unroll
        for (int bi = 0; bi < 4; ++bi)
          hv[bi] = *reinterpret_cast<const f4*>(&hA[bh * 4 + bi][kb]);
#pragma unroll
        for (int bi = 0; bi < 4; ++bi)
#pragma unroll
          for (int ci = 0; ci < 4; ++ci) {
            float a = acc[bi * 4 + ci];
            a = fmaf(hv[bi].x, wreg[ci][j].x, a);
            a = fmaf(hv[bi].y, wreg[ci][j].y, a);
            a = fmaf(hv[bi].z, wreg[ci][j].z, a);
            a = fmaf(hv[bi].w, wreg[ci][j].w, a);
            acc[bi * 4 + ci] = a;
          }
      }
#pragma unroll
      for (int o = 2; o < 64; o <<= 1)
#pragma unroll
        for (int i = 0; i < 16; ++i) acc[i] += __shfl_xor(acc[i], o, 64);
      if (lane < 2) {
#pragma unroll
        for (int bi = 0; bi < 4; ++bi) {
          f4 r;
          r.x = tanhf(acc[bi * 4 + 0] + xA[bi].x);
          r.y = tanhf(acc[bi * 4 + 1] + xA[bi].y);
          r.z = tanhf(acc[bi * 4 + 2] + xA[bi].z);
          r.w = tanhf(acc[bi * 4 + 3] + xA[bi].w);
          st_sys_x4(obA + (size_t)bi * TN + (size_t)t * N, r);
        }
      }
    }
    // ================= chain B (A's store-ack hides under this) ==========
    {
      float acc[16];
#pragma unroll
      for (int i = 0; i < 16; ++i) acc[i] = 0.f;
#pragma unroll
      for (int j = 0; j < 8; ++j) {
        const int kb = kp * 4 + 128 * j;
        f4 hv[4];
#pragma unroll
        for (int bi = 0; bi < 4; ++bi)
          hv[bi] = *reinterpret_cast<const f4*>(&hB[bh * 4 + bi][kb]);
#pragma unroll
        for (int bi = 0; bi < 4; ++bi)
#pragma unroll
          for (int ci = 0; ci < 4; ++ci) {
            float a = acc[bi * 4 + ci];
            a = fmaf(hv[bi].x, wreg[ci][j].x, a);
            a = fmaf(hv[bi].y, wreg[ci][j].y, a);
            a = fmaf(hv[bi].z, wreg[ci][j].z, a);
            a = fmaf(hv[bi].w, wreg[ci][j].w, a);
            acc[bi * 4 + ci] = a;
          }
      }
#pragma unroll
      for (int o = 2; o < 64; o <<= 1)
#pragma unroll
        for (int i = 0; i < 16; ++i) acc[i] += __shfl_xor(acc[i], o, 64);
      if (lane < 2) {
#pragma unroll
        for (int bi = 0; bi < 4; ++bi) {
          f4 r;
          r.x = tanhf(acc[bi * 4 + 0] + xB[bi].x);
          r.y = tanhf(acc[bi * 4 + 1] + xB[bi].y);
          r.z = tanhf(acc[bi * 4 + 2] + xB[bi].z);
          r.w = tanhf(acc[bi * 4 + 3] + xB[bi].w);
          st_sys_x4(obB + (size_t)bi * TN + (size_t)t * N, r);
        }
      }
    }

    wait_vm0();       // both chains' h_t stores acked at MALL
    __syncthreads();  // whole WG done
    if (t < T - 1) {
      if (tid == 0)  { arrive_cnt(bgA, t); pollf(bgA, t + 1); }
      if (tid == 64) { arrive_cnt(bgB, t); pollf(bgB, t + 1); }
      __syncthreads();
    }
  }
}

// ---------------------------------------------------------------------------
extern "C" void kernel_launch(void* const* d_in, const int* in_sizes, int n_in,
                              void* d_out, int out_size, void* d_ws,
                              size_t ws_size, hipStream_t stream) {
  const float* in_seq  = (const float*)d_in[0];  // (64,512,1024)
  const float* W_lower = (const float*)d_in[1];  // (1024,1024)
  const float* W_input = (const float*)d_in[2];  // (1024,1024)
  float* out = (float*)d_out;                    // (64,512,1024)
  float* Ws  = (float*)d_ws;                     // 4 MiB scratch

  symm_k<<<dim3(N / 16, N / 16), 256, 0, stream>>>(W_lower, Ws);
  xproj_gemm<<<dim3(N / 128, (BATCH * T) / 128), 256, 0, stream>>>(
      in_seq, W_input, out, BATCH * T);
  rnn_persist<<<NWG, 256, 0, stream>>>(out, Ws);
}

// Round 11
// 4121.044 us; speedup vs baseline: 1.7923x; 1.7923x over previous
//
#include <hip/hip_runtime.h>
#include <cstdint>
#include <cmath>

constexpr int BATCH = 64;
constexpr int T     = 512;
constexpr int N     = 1024;
constexpr int NWG   = 256;   // persistent workgroups (== CU count)
constexpr int NP    = N + 4; // padded LDS row

typedef float f4 __attribute__((ext_vector_type(4)));

struct alignas(128) PadInt { int v; int pad[31]; };
__device__ PadInt g_cnt[8];   // per-batch-group arrival counters (cumulative)
__device__ PadInt g_flag[8];  // per-batch-group completed-step counters

// ---- MALL-coherent access helpers (bypass L1+L2) ---------------------------
__device__ __forceinline__ f4 ld_sys_x4(const float* p) {
  f4 v;
  asm volatile("global_load_dwordx4 %0, %1, off sc0 sc1" : "=v"(v) : "v"(p));
  return v;  // NOT ready until wait_vm0()
}
__device__ __forceinline__ float ld_sys(const float* p) {
  float v;
  asm volatile("global_load_dword %0, %1, off sc0 sc1" : "=v"(v) : "v"(p));
  return v;  // NOT ready until wait_vm0()
}
__device__ __forceinline__ int ld_sys_i32(const int* p) {
  int v;
  asm volatile("global_load_dword %0, %1, off sc0 sc1\n\ts_waitcnt vmcnt(0)"
               : "=v"(v) : "v"(p) : "memory");
  return v;
}
__device__ __forceinline__ void st_sys(float* p, float v) {
  asm volatile("global_store_dword %0, %1, off sc0 sc1 nt" ::"v"(p), "v"(v)
               : "memory");
}
__device__ __forceinline__ void wait_vm0(void) {
  asm volatile("s_waitcnt vmcnt(0)" ::: "memory");
  __builtin_amdgcn_sched_barrier(0);
}

__device__ __forceinline__ void arrive_cnt(int bg, int t) {
  int old = __hip_atomic_fetch_add(&g_cnt[bg].v, 1, __ATOMIC_RELAXED,
                                   __HIP_MEMORY_SCOPE_AGENT);
  if (old == t * 64 + 63)  // last arriver of this step: publish
    __hip_atomic_store(&g_flag[bg].v, t + 1, __ATOMIC_RELAXED,
                       __HIP_MEMORY_SCOPE_AGENT);
}
__device__ __forceinline__ void pollf(int bg, int e) {
  while (ld_sys_i32(&g_flag[bg].v) < e) __builtin_amdgcn_s_sleep(1);
}

// ---------------------------------------------------------------------------
// W_self = 0.5*(W + W^T); also re-initializes the barrier state.
// ---------------------------------------------------------------------------
__global__ __launch_bounds__(256) void symm_k(const float* __restrict__ W,
                                              float* __restrict__ Ws) {
  if (blockIdx.x == 0 && blockIdx.y == 0 && threadIdx.x < 8) {
    __hip_atomic_store(&g_cnt[threadIdx.x].v, 0, __ATOMIC_RELAXED,
                       __HIP_MEMORY_SCOPE_AGENT);
    __hip_atomic_store(&g_flag[threadIdx.x].v, 0, __ATOMIC_RELAXED,
                       __HIP_MEMORY_SCOPE_AGENT);
  }
  int j = blockIdx.x * 16 + (threadIdx.x & 15);
  int i = blockIdx.y * 16 + (threadIdx.x >> 4);
  Ws[(size_t)i * N + j] = 0.5f * (W[(size_t)i * N + j] + W[(size_t)j * N + i]);
}

// ---------------------------------------------------------------------------
// x_proj = A (M x K) . B^T, B = W_input (N x K) row-major. 128x128 tile.
// XCD-aware swizzle: each XCD owns a contiguous 32-tile bm chunk x all 8 bn
// (bn fastest), so A is fetched once device-wide and B stays L2-resident.
// ---------------------------------------------------------------------------
__global__ __launch_bounds__(256) void xproj_gemm(const float* __restrict__ A,
                                                  const float* __restrict__ B,
                                                  float* __restrict__ C,
                                                  int M) {
  constexpr int BM = 128, BN = 128, BK = 16;
  __shared__ float As[BK][BM + 4];
  __shared__ float Bs[BK][BN + 4];

  const int tid = threadIdx.x;
  const int lin = blockIdx.x + gridDim.x * blockIdx.y;  // 0..2047
  const int sw  = ((lin & 7) << 8) + (lin >> 3);        // bijective (2048%8==0)
  const int bm  = sw >> 3;                              // 0..255
  const int bn  = sw & 7;                               // 0..7
  const int tx = tid & 15, ty = tid >> 4;
  const int K = N;

  float acc[8][8];
#pragma unroll
  for (int i = 0; i < 8; ++i)
#pragma unroll
    for (int j = 0; j < 8; ++j) acc[i][j] = 0.f;

  for (int kt = 0; kt < K; kt += BK) {
#pragma unroll
    for (int s = 0; s < 2; ++s) {
      int f = tid + s * 256;
      int row = f >> 2, kq = f & 3;
      float4 a = *reinterpret_cast<const float4*>(
          &A[(size_t)(bm * BM + row) * K + kt + kq * 4]);
      As[kq * 4 + 0][row] = a.x;
      As[kq * 4 + 1][row] = a.y;
      As[kq * 4 + 2][row] = a.z;
      As[kq * 4 + 3][row] = a.w;
      float4 b = *reinterpret_cast<const float4*>(
          &B[(size_t)(bn * BN + row) * K + kt + kq * 4]);
      Bs[kq * 4 + 0][row] = b.x;
      Bs[kq * 4 + 1][row] = b.y;
      Bs[kq * 4 + 2][row] = b.z;
      Bs[kq * 4 + 3][row] = b.w;
    }
    __syncthreads();

#pragma unroll
    for (int k = 0; k < BK; ++k) {
      float a[8], b[8];
      *reinterpret_cast<float4*>(&a[0]) =
          *reinterpret_cast<const float4*>(&As[k][ty * 8]);
      *reinterpret_cast<float4*>(&a[4]) =
          *reinterpret_cast<const float4*>(&As[k][ty * 8 + 4]);
      *reinterpret_cast<float4*>(&b[0]) =
          *reinterpret_cast<const float4*>(&Bs[k][tx * 8]);
      *reinterpret_cast<float4*>(&b[4]) =
          *reinterpret_cast<const float4*>(&Bs[k][tx * 8 + 4]);
#pragma unroll
      for (int i = 0; i < 8; ++i)
#pragma unroll
        for (int j = 0; j < 8; ++j) acc[i][j] = fmaf(a[i], b[j], acc[i][j]);
    }
    __syncthreads();
  }

#pragma unroll
  for (int i = 0; i < 8; ++i) {
    size_t row = (size_t)bm * BM + ty * 8 + i;
#pragma unroll
    for (int j = 0; j < 8; j += 4) {
      *reinterpret_cast<float4*>(&C[row * N + bn * BN + tx * 8 + j]) =
          *reinterpret_cast<const float4*>(&acc[i][j]);
    }
  }
}

// ---------------------------------------------------------------------------
// Persistent recurrence: R9's proven micro-tile + merged staging.
// 256 WGs x 256 thr, 1 WG/CU (LDS 100 KiB).  WG (p = wg&3, cg = wg>>2):
// cols cg*16..+15 for batch groups bgA=2p, bgB=2p+1 (8 batches each).
// Per step: issue BOTH chains' h+xp loads, one vmcnt wait, one staging
// barrier; compute A, store A (no ack-wait), compute B (A's ack hides
// here), store B, single ack-wait, concurrent arrive+poll per chain.
// 8 independent 64-WG barriers, relaxed atomics, MALL-coherent data path.
// ---------------------------------------------------------------------------
__global__ __launch_bounds__(256, 1) void rnn_persist(
    float* __restrict__ out, const float* __restrict__ Ws) {
  const int tid = threadIdx.x;
  const int wg  = blockIdx.x;
  const int p   = wg & 3;
  const int cg  = wg >> 2;
  const int bgA = 2 * p, bgB = 2 * p + 1;
  const int m0  = cg * 16;
  const int b0A = bgA * 8, b0B = bgB * 8;
  const size_t TN = (size_t)T * N;

  // 100 KiB forced LDS (1 WG/CU).  W-staging phase aliases the h buffers.
  __shared__ __align__(16) char lds_raw[102400];
  float (*Wl)[NP]   = reinterpret_cast<float(*)[NP]>(lds_raw);  // 16 rows
  float (*hA)[NP]   = reinterpret_cast<float(*)[NP]>(lds_raw);  // 8 rows
  float (*hB)[NP]   = reinterpret_cast<float(*)[NP]>(lds_raw + 8 * NP * 4);
  float (*preA)[17] = reinterpret_cast<float(*)[17]>(lds_raw + 16 * NP * 4);
  float (*preB)[17] = reinterpret_cast<float(*)[17]>(lds_raw + 16 * NP * 4 + 544);

  const int l  = tid & 63;
  const int v  = tid >> 6;
  const int kp = l >> 2;            // k partition (16-way)
  const int c2 = l & 3;
  const int bh = v & 1;             // batch half (4 rows)
  const int cp = (v >> 1) * 4 + c2; // col pair 0..7

  // ---- W slice -> LDS (coalesced) -> per-thread register fragment ----
#pragma unroll
  for (int r = 0; r < 16; ++r)
    *reinterpret_cast<float4*>(&Wl[r][tid * 4]) =
        *reinterpret_cast<const float4*>(&Ws[(size_t)(m0 + r) * N + tid * 4]);
  __syncthreads();
  f4 wreg[2][16];  // rows (cols of output) cp*2, cp*2+1; k = kp*4 + 64*j
#pragma unroll
  for (int ci = 0; ci < 2; ++ci)
#pragma unroll
    for (int j = 0; j < 16; ++j)
      wreg[ci][j] =
          *reinterpret_cast<const f4*>(&Wl[cp * 2 + ci][kp * 4 + 64 * j]);
  __syncthreads();  // LDS now reused as hA/hB

  const int srow = tid >> 5;   // staging batch row 0..7
  const int scol = tid & 31;   // staging chunk
  const int rs   = tid >> 4;   // store row (tid<128)
  const int cs   = tid & 15;   // store col

  const float* hbA = out + (size_t)(b0A + srow) * TN + 4 * scol;
  const float* hbB = out + (size_t)(b0B + srow) * TN + 4 * scol;
  float* myoutA = out + (size_t)(b0A + rs) * TN + m0 + cs;
  float* myoutB = out + (size_t)(b0B + rs) * TN + m0 + cs;
  float xpA = 0.f, xpB = 0.f;

  // ---- t = 0: h_0 = tanh(x_proj_0) ----
  if (tid < 128) { xpA = ld_sys(myoutA); xpB = ld_sys(myoutB); }
  wait_vm0();
  if (tid < 128) {
    st_sys(myoutA, tanhf(xpA));
    st_sys(myoutB, tanhf(xpB));
  }
  wait_vm0();
  __syncthreads();
  if (tid == 0)  { arrive_cnt(bgA, 0); pollf(bgA, 1); }
  if (tid == 64) { arrive_cnt(bgB, 0); pollf(bgB, 1); }
  __syncthreads();

  for (int t = 1; t < T; ++t) {
    // ---- issue ALL staging loads (both chains), single wait ----
    f4 tA[8], tB[8];
    const float* hsA = hbA + (size_t)(t - 1) * N;
    const float* hsB = hbB + (size_t)(t - 1) * N;
#pragma unroll
    for (int q = 0; q < 8; ++q) tA[q] = ld_sys_x4(hsA + 128 * q);
#pragma unroll
    for (int q = 0; q < 8; ++q) tB[q] = ld_sys_x4(hsB + 128 * q);
    if (tid < 128) {
      xpA = ld_sys(myoutA + (size_t)t * N);
      xpB = ld_sys(myoutB + (size_t)t * N);
    }
    wait_vm0();
#pragma unroll
    for (int q = 0; q < 8; ++q)
      *reinterpret_cast<f4*>(&hA[srow][4 * scol + 128 * q]) = tA[q];
#pragma unroll
    for (int q = 0; q < 8; ++q)
      *reinterpret_cast<f4*>(&hB[srow][4 * scol + 128 * q]) = tB[q];
    __syncthreads();

    // ================= chain A =================
    {
      float acc[8];
#pragma unroll
      for (int i = 0; i < 8; ++i) acc[i] = 0.f;
#pragma unroll
      for (int j = 0; j < 16; ++j) {
        const int kb = kp * 4 + 64 * j;
        f4 hv[4];
#pragma unroll
        for (int bi = 0; bi < 4; ++bi)
          hv[bi] = *reinterpret_cast<const f4*>(&hA[bh * 4 + bi][kb]);
#pragma unroll
        for (int bi = 0; bi < 4; ++bi)
#pragma unroll
          for (int ci = 0; ci < 2; ++ci) {
            float a = acc[bi * 2 + ci];
            a = fmaf(hv[bi].x, wreg[ci][j].x, a);
            a = fmaf(hv[bi].y, wreg[ci][j].y, a);
            a = fmaf(hv[bi].z, wreg[ci][j].z, a);
            a = fmaf(hv[bi].w, wreg[ci][j].w, a);
            acc[bi * 2 + ci] = a;
          }
      }
#pragma unroll
      for (int o = 4; o < 64; o <<= 1)
#pragma unroll
        for (int i = 0; i < 8; ++i) acc[i] += __shfl_xor(acc[i], o, 64);
      if (kp == 0) {
#pragma unroll
        for (int bi = 0; bi < 4; ++bi)
#pragma unroll
          for (int ci = 0; ci < 2; ++ci)
            preA[bh * 4 + bi][cp * 2 + ci] = acc[bi * 2 + ci];
      }
    }
    __syncthreads();
    if (tid < 128)
      st_sys(myoutA + (size_t)t * N, tanhf(preA[rs][cs] + xpA));  // no wait

    // ================= chain B (A's store-ack hides here) =================
    {
      float acc[8];
#pragma unroll
      for (int i = 0; i < 8; ++i) acc[i] = 0.f;
#pragma unroll
      for (int j = 0; j < 16; ++j) {
        const int kb = kp * 4 + 64 * j;
        f4 hv[4];
#pragma unroll
        for (int bi = 0; bi < 4; ++bi)
          hv[bi] = *reinterpret_cast<const f4*>(&hB[bh * 4 + bi][kb]);
#pragma unroll
        for (int bi = 0; bi < 4; ++bi)
#pragma unroll
          for (int ci = 0; ci < 2; ++ci) {
            float a = acc[bi * 2 + ci];
            a = fmaf(hv[bi].x, wreg[ci][j].x, a);
            a = fmaf(hv[bi].y, wreg[ci][j].y, a);
            a = fmaf(hv[bi].z, wreg[ci][j].z, a);
            a = fmaf(hv[bi].w, wreg[ci][j].w, a);
            acc[bi * 2 + ci] = a;
          }
      }
#pragma unroll
      for (int o = 4; o < 64; o <<= 1)
#pragma unroll
        for (int i = 0; i < 8; ++i) acc[i] += __shfl_xor(acc[i], o, 64);
      if (kp == 0) {
#pragma unroll
        for (int bi = 0; bi < 4; ++bi)
#pragma unroll
          for (int ci = 0; ci < 2; ++ci)
            preB[bh * 4 + bi][cp * 2 + ci] = acc[bi * 2 + ci];
      }
    }
    __syncthreads();
    if (tid < 128)
      st_sys(myoutB + (size_t)t * N, tanhf(preB[rs][cs] + xpB));

    wait_vm0();       // both chains' h_t stores acked at MALL
    __syncthreads();  // whole WG done
    if (t < T - 1) {
      if (tid == 0)  { arrive_cnt(bgA, t); pollf(bgA, t + 1); }
      if (tid == 64) { arrive_cnt(bgB, t); pollf(bgB, t + 1); }
      __syncthreads();
    }
  }
}

// ---------------------------------------------------------------------------
extern "C" void kernel_launch(void* const* d_in, const int* in_sizes, int n_in,
                              void* d_out, int out_size, void* d_ws,
                              size_t ws_size, hipStream_t stream) {
  const float* in_seq  = (const float*)d_in[0];  // (64,512,1024)
  const float* W_lower = (const float*)d_in[1];  // (1024,1024)
  const float* W_input = (const float*)d_in[2];  // (1024,1024)
  float* out = (float*)d_out;                    // (64,512,1024)
  float* Ws  = (float*)d_ws;                     // 4 MiB scratch

  symm_k<<<dim3(N / 16, N / 16), 256, 0, stream>>>(W_lower, Ws);
  xproj_gemm<<<dim3(N / 128, (BATCH * T) / 128), 256, 0, stream>>>(
      in_seq, W_input, out, BATCH * T);
  rnn_persist<<<NWG, 256, 0, stream>>>(out, Ws);
}